// Round 15
// baseline (886.353 us; speedup 1.0000x reference)
//
#include <hip/hip_runtime.h>
#include <math.h>

#define D_ 512
#define H_ 8

typedef short bf16x8 __attribute__((ext_vector_type(8)));
typedef float f32x4 __attribute__((ext_vector_type(4)));

__device__ __forceinline__ unsigned short f2bf(float x) {
  unsigned int u = __float_as_uint(x);
  unsigned int r = (u + 0x7fff + ((u >> 16) & 1)) >> 16;
  return (unsigned short)r;
}
__device__ __forceinline__ float bf2f(unsigned short b) {
  return __uint_as_float(((unsigned int)b) << 16);
}

// Packed-B index: PK[nt][kt][kk][njj][lane=q*16+rl][e]; frag elem j of the
// MFMA B-operand for (n, k-slice) = Bt[n][kt*64+kk*32+q*8+j]  (identity
// verified against the round-8 LDS+swizzle path).
__device__ __forceinline__ long pk_idx(int n, int k) {
  int nt = n >> 7, njj = (n >> 4) & 7, rl = n & 15;
  int kt = k >> 6, kk = (k >> 5) & 1, q = (k >> 3) & 3, e = k & 7;
  return ((((long)(nt * 8 + kt) * 2 + kk) * 8 + njj) * 64 + (q * 16 + rl)) * 8 + e;
}

// ================= prep: cvt + fuse-weights(->PK) + transposes(->PK) ========
struct PrepArgs {
  const float *hA, *hP;
  unsigned short *hA16, *hP16;
  const float *fWin[6], *fbin[6], *frel[6];
  unsigned short *fpk[6];
  int fnoff[6];
  float *fbf[6];
  const float *tW[4];
  unsigned short *tpk[4];
  const float *cin[2];
  float *cout[2];
  int *degree;
  int NT;
  int b1, b2, b3, b4, b5;
};

__global__ __launch_bounds__(512) void prep_kernel(PrepArgs p) {
  const int b = blockIdx.x, t = threadIdx.x;
  if (b < p.b2) {                    // bf16 convert (8 elems/thread)
    const float* in; unsigned short* out; long i;
    if (b < p.b1) { in = p.hA; out = p.hA16; i = (long)b * 512 + t; }
    else          { in = p.hP; out = p.hP16; i = (long)(b - p.b1) * 512 + t; }
    float4 a = ((const float4*)in)[i * 2];
    float4 c = ((const float4*)in)[i * 2 + 1];
    bf16x8 o;
    o[0] = (short)f2bf(a.x); o[1] = (short)f2bf(a.y);
    o[2] = (short)f2bf(a.z); o[3] = (short)f2bf(a.w);
    o[4] = (short)f2bf(c.x); o[5] = (short)f2bf(c.y);
    o[6] = (short)f2bf(c.z); o[7] = (short)f2bf(c.w);
    ((bf16x8*)out)[i] = o;
  } else if (b < p.b3) {             // fused rel-weight -> packed B
    int idx = b - p.b2;
    int job = idx / 513, row = idx - job * 513;   // row = k (512 => bias)
    int h = t >> 6, e = t & 63;
    const float* src = (row < D_) ? (p.fWin[job] + (long)row * D_) : p.fbin[job];
    const float* rl = p.frel[job] + h * 64 * 64;
    float acc = 0.f;
#pragma unroll 16
    for (int d = 0; d < 64; ++d)
      acc = fmaf(src[h * 64 + d], rl[d * 64 + e], acc);
    if (row < D_) p.fpk[job][pk_idx(p.fnoff[job] + t, row)] = f2bf(acc);
    else p.fbf[job][t] = acc;
  } else if (b < p.b4) {             // transpose-convert 512x512 -> packed B
    int idx = b - p.b3;
    int job = idx >> 9, n = idx & 511;
    p.tpk[job][pk_idx(n, t)] = f2bf(p.tW[job][(long)t * D_ + n]);
  } else if (b < p.b5) {             // bias copies
    int job = b - p.b4;
    p.cout[job][t] = p.cin[job][t];
  } else {                           // degree zero-fill
    int i = (b - p.b5) * 512 + t;
    if (i < p.NT) p.degree[i] = 0;
  }
}

// ================= CSR build: hist -> scan -> scatter ========================
__global__ void hist_kernel(const int* __restrict__ w_dst,
                            const int* __restrict__ c_dst,
                            const int* __restrict__ b_dst,
                            int* __restrict__ degree, int E, int NP) {
  int i = blockIdx.x * blockDim.x + threadIdx.x;
  if (i >= 3 * E) return;
  int r = i / E, e = i - r * E;
  int d, base;
  if (r == 0)      { d = w_dst[e]; base = 0; }
  else if (r == 1) { d = c_dst[e]; base = NP; }
  else             { d = b_dst[e]; base = 2 * NP; }
  atomicAdd(degree + base + d, 1);
}

__global__ void scan1_kernel(const int* __restrict__ in, int* __restrict__ out,
                             int* __restrict__ aux, int n) {
  __shared__ int tmp[256];
  int t = threadIdx.x;
  int i = blockIdx.x * 256 + t;
  int v = (i < n) ? in[i] : 0;
  tmp[t] = v;
  __syncthreads();
#pragma unroll
  for (int d = 1; d < 256; d <<= 1) {
    int add = (t >= d) ? tmp[t - d] : 0;
    __syncthreads();
    tmp[t] += add;
    __syncthreads();
  }
  if (i < n) out[i] = tmp[t] - v;   // exclusive
  if (t == 255) aux[blockIdx.x] = tmp[255];
}

__global__ void scan2_kernel(int* __restrict__ aux, int nb) {
  __shared__ int tmp[1024];
  int t = threadIdx.x;
  int v = (t < nb) ? aux[t] : 0;
  tmp[t] = v;
  __syncthreads();
#pragma unroll
  for (int d = 1; d < 1024; d <<= 1) {
    int add = (t >= d) ? tmp[t - d] : 0;
    __syncthreads();
    tmp[t] += add;
    __syncthreads();
  }
  if (t < nb) aux[t] = tmp[t] - v;  // exclusive block offsets
}

__global__ void scan3_kernel(int* __restrict__ starts, int* __restrict__ cursor,
                             const int* __restrict__ aux, int n) {
  int i = blockIdx.x * 256 + threadIdx.x;
  if (i >= n) return;
  int s = starts[i] + aux[blockIdx.x];
  starts[i] = s;
  cursor[i] = s;
}

__global__ void scatter_kernel(const int* __restrict__ w_src, const int* __restrict__ w_dst,
                               const int* __restrict__ c_src, const int* __restrict__ c_dst,
                               const int* __restrict__ b_src, const int* __restrict__ b_dst,
                               int* __restrict__ cursor, int* __restrict__ csr,
                               int E, int NP) {
  int i = blockIdx.x * blockDim.x + threadIdx.x;
  if (i >= 3 * E) return;
  int r = i / E, e = i - r * E;
  int s, d, base;
  if (r == 0)      { s = w_src[e]; d = w_dst[e]; base = 0; }
  else if (r == 1) { s = c_src[e]; d = c_dst[e]; base = NP; }
  else             { s = b_src[e]; d = b_dst[e]; base = 2 * NP; }
  int pos = atomicAdd(cursor + base + d, 1);
  csr[pos] = s;
}

// ================= fused per-node edge attention (papers + authors) ==========
__global__ __launch_bounds__(256) void attn_all(
    const unsigned short* __restrict__ Pq,
    const unsigned short* __restrict__ Akw, const unsigned short* __restrict__ Avw,
    const unsigned short* __restrict__ Pkc, const unsigned short* __restrict__ Pvc,
    const unsigned short* __restrict__ Aq,
    const unsigned short* __restrict__ Pkb, const unsigned short* __restrict__ Pvb,
    const int* __restrict__ csr, const int* __restrict__ starts,
    const int* __restrict__ degree, const float* __restrict__ pri,
    unsigned short* __restrict__ t16, int NP, int NA, int NAp) {
  long gid = (long)blockIdx.x * blockDim.x + threadIdx.x;
  int gw = (int)(gid >> 6);
  if (gw >= NP + NAp) return;
  int lane = threadIdx.x & 63;
  int h = lane >> 3, off = (lane & 7) << 3;

  const unsigned short* q;
  long orow;
  int node;
  const int paper = gw < NP;
  if (paper) {
    node = gw; q = Pq;
    orow = (long)(NAp + node) * D_ + h * 64 + off;
  } else {
    int aw = gw - NP;
    orow = (long)aw * D_ + h * 64 + off;
    if (aw >= NA) {                 // zero the alignment-pad rows
      bf16x8 z;
#pragma unroll
      for (int r = 0; r < 8; ++r) z[r] = 0;
      *(bf16x8*)(t16 + orow) = z;
      return;
    }
    node = aw; q = Aq;
  }

  bf16x8 qv = *(const bf16x8*)(q + (long)node * D_ + h * 64 + off);
  float qf[8];
#pragma unroll
  for (int r = 0; r < 8; ++r) qf[r] = bf2f((unsigned short)qv[r]);

  float res[8] = {};

  auto process = [&](const unsigned short* K, const unsigned short* V,
                     int nodeabs, float ps) {
    int st = starts[nodeabs], dg = degree[nodeabs];
    float m = -INFINITY, l = 0.f;
    float acc[8] = {};
    for (int i = 0; i < dg; ++i) {
      int s = csr[st + i];
      const long ro = (long)s * D_ + h * 64 + off;
      bf16x8 kv = *(const bf16x8*)(K + ro);
      bf16x8 vv = *(const bf16x8*)(V + ro);
      float dot = 0.f;
#pragma unroll
      for (int r = 0; r < 8; ++r)
        dot = fmaf(qf[r], bf2f((unsigned short)kv[r]), dot);
      dot += __shfl_xor(dot, 1);
      dot += __shfl_xor(dot, 2);
      dot += __shfl_xor(dot, 4);
      float sc = dot * ps;
      float mn = fmaxf(m, sc);
      float scale = __expf(m - mn);   // m=-inf first edge -> 0
      float pv = __expf(sc - mn);
      l = l * scale + pv;
#pragma unroll
      for (int r = 0; r < 8; ++r)
        acc[r] = acc[r] * scale + pv * bf2f((unsigned short)vv[r]);
      m = mn;
    }
    if (l > 0.f) {
      float inv = 1.f / l;
#pragma unroll
      for (int r = 0; r < 8; ++r) res[r] += acc[r] * inv;
    }
  };

  float outscale;
  if (paper) {
    process(Akw, Avw, node, pri[h] * 0.125f);
    process(Pkc, Pvc, NP + node, pri[8 + h] * 0.125f);
    outscale = 0.5f;
  } else {
    process(Pkb, Pvb, 2 * NP + node, pri[16 + h] * 0.125f);
    outscale = 1.0f;
  }

  bf16x8 o;
#pragma unroll
  for (int r = 0; r < 8; ++r) o[r] = (short)f2bf(res[r] * outscale);
  *(bf16x8*)(t16 + orow) = o;
}

// ================= MFMA GEMM: 128x128 tile, A in 3-slot LDS ring, B in regs ==
// B comes straight from the L2-resident packed buffer (coalesced dwordx4 per
// fragment) -> LDS = A only (48 KiB) -> 3 blocks/CU for cross-block TLP.
// Per tile: vmcnt(4) [A(t) proven done, A(t+1) in flight] + one barrier;
// B loads (compiler auto-waits cover them); ds_read A; stage A(t+2) into the
// slot freed at tile t-1; setprio MFMA.
__device__ __forceinline__ void gload_lds16(const void* g, void* l) {
  __builtin_amdgcn_global_load_lds(
      (const __attribute__((address_space(1))) void*)g,
      (__attribute__((address_space(3))) void*)l, 16, 0, 0);
}

#define GEMM_CORE(A_PTR, PK_PTR)                                              \
  f32x4 acc[4][4] = {};                                                       \
  const int rr = lane & 15;                                                   \
  const int qk = lane >> 4;                                                   \
  const int rx = (rr & 7) << 4;                                               \
  auto STAGE_A = [&](int slot, int tile) {                                    \
    const int k0 = tile * 64 + swz;                                           \
    _Pragma("unroll")                                                         \
    for (int j = 0; j < 4; ++j) {                                             \
      int gr = bm + srow + j * 32;                                            \
      if (gr >= M) gr = M - 1;                                                \
      gload_lds16((A_PTR) + (long)gr * D_ + k0,                               \
                  &As[slot][j * 2048 + wave * 512]);                          \
    }                                                                         \
  };                                                                          \
  STAGE_A(0, 0); STAGE_A(1, 1);                                               \
  _Pragma("unroll")                                                           \
  for (int t = 0; t < 8; ++t) {                                               \
    asm volatile("s_waitcnt vmcnt(4)" ::: "memory");                          \
    __builtin_amdgcn_s_barrier();                                             \
    asm volatile("" ::: "memory");                                            \
    bf16x8 bfr[8];                                                            \
    _Pragma("unroll")                                                         \
    for (int kk = 0; kk < 2; ++kk)                                            \
      _Pragma("unroll")                                                       \
      for (int nj = 0; nj < 4; ++nj)                                          \
        bfr[kk * 4 + nj] = *(const bf16x8*)((PK_PTR) +                        \
            ((long)((nt * 8 + t) * 16 + kk * 8 + (wn >> 4) + nj) * 64 +       \
             lane) * 8);                                                      \
    bf16x8 af[8];                                                             \
    const char* ab = (const char*)&As[t % 3][0];                              \
    _Pragma("unroll")                                                         \
    for (int kk = 0; kk < 2; ++kk) {                                          \
      const int cs = (kk * 64 + qk * 16) ^ rx;                                \
      _Pragma("unroll")                                                       \
      for (int mi = 0; mi < 4; ++mi)                                          \
        af[kk * 4 + mi] =                                                     \
            *(const bf16x8*)(ab + (wm + mi * 16 + rr) * 128 + cs);            \
    }                                                                         \
    if (t + 2 < 8) STAGE_A((t + 2) % 3, t + 2);                               \
    __builtin_amdgcn_s_setprio(1);                                            \
    _Pragma("unroll")                                                         \
    for (int kk = 0; kk < 2; ++kk)                                            \
      _Pragma("unroll")                                                       \
      for (int mi = 0; mi < 4; ++mi)                                          \
        _Pragma("unroll")                                                     \
        for (int nj = 0; nj < 4; ++nj)                                        \
          acc[mi][nj] = __builtin_amdgcn_mfma_f32_16x16x32_bf16(              \
              af[kk * 4 + mi], bfr[kk * 4 + nj], acc[mi][nj], 0, 0, 0);       \
    __builtin_amdgcn_s_setprio(0);                                            \
    asm volatile("" ::: "memory");                                            \
  }

struct ProjArgs {
  const unsigned short *A0, *A1;
  const unsigned short *PK0, *PK1;
  const float *bias0, *bias1;
  void* outs[8];                    // 0-2 author, 3-7 paper
  int M0, M1, split;                // split = tA128*12
};

struct OutArgs {
  const unsigned short* A;          // combined t16
  const unsigned short *PK0, *PK1;
  const float *bias0, *bias1;
  const float *H0, *H1;
  const float* skip;
  float *o0, *o1;
  int mtsplit, NAp, M0, M1;
};

__global__ __launch_bounds__(256, 3) void gemm_proj(ProjArgs pa) {
  __shared__ unsigned short As[3][128 * 64];   // 48 KiB

  const int nwg = gridDim.x, orig = blockIdx.x;
  const int q8 = nwg >> 3, r8 = nwg & 7;
  const int xcd = orig & 7, pos = orig >> 3;
  const int wgid =
      (xcd < r8 ? xcd * (q8 + 1) : r8 * (q8 + 1) + (xcd - r8) * q8) + pos;

  int reg, mt, nt;
  if (wgid < pa.split) { reg = 0; mt = wgid / 12; nt = wgid - mt * 12; }
  else { int r = wgid - pa.split; reg = 1; mt = r / 20; nt = r - mt * 20; }
  const unsigned short* A  = reg ? pa.A1 : pa.A0;
  const unsigned short* PK = reg ? pa.PK1 : pa.PK0;
  const float* bias = reg ? pa.bias1 : pa.bias0;
  const int M = reg ? pa.M1 : pa.M0;
  const int bm = mt * 128, bn = nt * 128;

  const int tid = threadIdx.x;
  const int wave = tid >> 6, lane = tid & 63;
  const int wm = (wave >> 1) * 64;
  const int wn = (wave & 1) * 64;
  const int srow = tid >> 3;                    // 0..31
  const int swz = ((tid & 7) ^ (srow & 7)) * 8;

  GEMM_CORE(A, PK)

  const int cr = (lane >> 4) * 4;
  const int cc = lane & 15;
  const int matu = (bn + wn) >> 9;
  const int wcb = (bn + wn) & 511;
  unsigned short* ob16 = (unsigned short*)pa.outs[(reg ? 3 : 0) + matu];
#pragma unroll
  for (int mi = 0; mi < 4; ++mi) {
    int rowb = bm + wm + mi * 16 + cr;
#pragma unroll
    for (int nj = 0; nj < 4; ++nj) {
      float bb = bias[bn + wn + nj * 16 + cc];
#pragma unroll
      for (int r = 0; r < 4; ++r) {
        int row = rowb + r;
        if (row >= M) continue;
        ob16[(long)row * D_ + wcb + nj * 16 + cc] = f2bf(acc[mi][nj][r] + bb);
      }
    }
  }
}

__global__ __launch_bounds__(256, 3) void gemm_out(OutArgs oa) {
  __shared__ unsigned short As[3][128 * 64];

  const int nwg = gridDim.x, orig = blockIdx.x;
  const int q8 = nwg >> 3, r8 = nwg & 7;
  const int xcd = orig & 7, pos = orig >> 3;
  const int wgid =
      (xcd < r8 ? xcd * (q8 + 1) : r8 * (q8 + 1) + (xcd - r8) * q8) + pos;

  const int bmt = wgid >> 2;
  const int nt = wgid & 3;
  const int bn = nt * 128;
  const int reg = bmt >= oa.mtsplit;
  const int bm = (reg ? bmt - oa.mtsplit : bmt) * 128;   // region-local
  const int abase = reg ? oa.NAp : 0;
  const int M = reg ? oa.M1 : oa.M0;
  const unsigned short* A  = oa.A + (long)abase * D_;
  const unsigned short* PK = reg ? oa.PK1 : oa.PK0;
  const float* bias = reg ? oa.bias1 : oa.bias0;
  const float* Hres = reg ? oa.H1 : oa.H0;
  float* outp = reg ? oa.o1 : oa.o0;

  const int tid = threadIdx.x;
  const int wave = tid >> 6, lane = tid & 63;
  const int wm = (wave >> 1) * 64;
  const int wn = (wave & 1) * 64;
  const int srow = tid >> 3;
  const int swz = ((tid & 7) ^ (srow & 7)) * 8;

  GEMM_CORE(A, PK)

  float sv = oa.skip[reg];
  float alpha = 1.f / (1.f + expf(-sv));
  float beta = 1.f - alpha;
  const int cr = (lane >> 4) * 4;
  const int cc = lane & 15;
#pragma unroll
  for (int mi = 0; mi < 4; ++mi) {
    int rowb = bm + wm + mi * 16 + cr;
#pragma unroll
    for (int nj = 0; nj < 4; ++nj) {
      int col = bn + wn + nj * 16 + cc;
      float bb = bias[col];
#pragma unroll
      for (int r = 0; r < 4; ++r) {
        int row = rowb + r;
        if (row >= M) continue;
        float val = acc[mi][nj][r] + bb;
        val = val * alpha + Hres[(long)row * D_ + col] * beta;
        outp[(long)row * D_ + col] = val;
      }
    }
  }
}

// ================= launch =====================================================
extern "C" void kernel_launch(void* const* d_in, const int* in_sizes, int n_in,
                              void* d_out, int out_size, void* d_ws, size_t ws_size,
                              hipStream_t stream) {
  const float* h_author = (const float*)d_in[0];
  const float* h_paper  = (const float*)d_in[1];
  const int* w_src = (const int*)d_in[2];
  const int* w_dst = (const int*)d_in[3];
  const int* c_src = (const int*)d_in[4];
  const int* c_dst = (const int*)d_in[5];
  const int* b_src = (const int*)d_in[6];
  const int* b_dst = (const int*)d_in[7];
  const float* Wk = (const float*)d_in[8];
  const float* bk = (const float*)d_in[9];
  const float* Wq = (const float*)d_in[10];
  const float* bq = (const float*)d_in[11];
  const float* Wv = (const float*)d_in[12];
  const float* bv = (const float*)d_in[13];
  const float* Wa = (const float*)d_in[14];
  const float* ba = (const float*)d_in[15];
  const float* rel_att = (const float*)d_in[16];
  const float* rel_msg = (const float*)d_in[17];
  const float* rel_pri = (const float*)d_in[18];
  const float* skip = (const float*)d_in[19];

  const int NA = in_sizes[0] / D_;
  const int NP = in_sizes[1] / D_;
  const int E  = in_sizes[2];
  const int NT = 2 * NP + NA;
  const int tA = (NA + 127) / 128;       // author M tiles (BM=128)
  const int tP = (NP + 127) / 128;       // paper M tiles
  const int NAp = tA * 128;              // aligned author row count

  char* w = (char*)d_ws;
  auto alloc = [&](long bytes) {
    char* p = w;
    w += (bytes + 255) & ~255L;
    return p;
  };
  unsigned short* hA16 = (unsigned short*)alloc((long)NA * D_ * 2);
  unsigned short* hP16 = (unsigned short*)alloc((long)NP * D_ * 2);
  unsigned short* Pq   = (unsigned short*)alloc((long)NP * D_ * 2);
  unsigned short* Pkc  = (unsigned short*)alloc((long)NP * D_ * 2);
  unsigned short* Pvc  = (unsigned short*)alloc((long)NP * D_ * 2);
  unsigned short* Pkb  = (unsigned short*)alloc((long)NP * D_ * 2);
  unsigned short* Pvb  = (unsigned short*)alloc((long)NP * D_ * 2);
  unsigned short* Aq   = (unsigned short*)alloc((long)NA * D_ * 2);
  unsigned short* Akw  = (unsigned short*)alloc((long)NA * D_ * 2);
  unsigned short* Avw  = (unsigned short*)alloc((long)NA * D_ * 2);
  unsigned short* t16  = (unsigned short*)alloc((long)(NAp + NP) * D_ * 2);
  unsigned short* PKP  = (unsigned short*)alloc((long)2560 * D_ * 2);
  unsigned short* PKA  = (unsigned short*)alloc((long)1536 * D_ * 2);
  float* bfP           = (float*)alloc(2560 * 4);
  float* bfA           = (float*)alloc(1536 * 4);
  unsigned short* PK0  = (unsigned short*)alloc((long)D_ * D_ * 2);
  unsigned short* PK1  = (unsigned short*)alloc((long)D_ * D_ * 2);
  int* degree          = (int*)alloc((long)NT * 4);
  int* starts          = (int*)alloc((long)NT * 4);
  int* cursor          = (int*)alloc((long)NT * 4);
  int* csr             = (int*)alloc((long)3 * E * 4);
  int* aux             = (int*)alloc(((long)NT / 256 + 2) * 4);

  const long WD = (long)D_ * D_;
  const long RS = (long)H_ * 64 * 64;

  float* out_a = (float*)d_out;
  float* out_p = out_a + (long)NA * D_;

  // ---- 1 dispatch: all precompute ----
  {
    PrepArgs p;
    p.hA = h_author; p.hP = h_paper; p.hA16 = hA16; p.hP16 = hP16;
    // fuse jobs 0-3: paper PK segments; 4-5: author PK segments
    p.fWin[0] = Wk + WD; p.fbin[0] = bk + D_; p.frel[0] = rel_att + RS;
    p.fpk[0] = PKP; p.fnoff[0] = 512;  p.fbf[0] = bfP + 512;
    p.fWin[1] = Wv + WD; p.fbin[1] = bv + D_; p.frel[1] = rel_msg + RS;
    p.fpk[1] = PKP; p.fnoff[1] = 1024; p.fbf[1] = bfP + 1024;
    p.fWin[2] = Wk + WD; p.fbin[2] = bk + D_; p.frel[2] = rel_att + 2 * RS;
    p.fpk[2] = PKP; p.fnoff[2] = 1536; p.fbf[2] = bfP + 1536;
    p.fWin[3] = Wv + WD; p.fbin[3] = bv + D_; p.frel[3] = rel_msg + 2 * RS;
    p.fpk[3] = PKP; p.fnoff[3] = 2048; p.fbf[3] = bfP + 2048;
    p.fWin[4] = Wk;      p.fbin[4] = bk;      p.frel[4] = rel_att;
    p.fpk[4] = PKA; p.fnoff[4] = 512;  p.fbf[4] = bfA + 512;
    p.fWin[5] = Wv;      p.fbin[5] = bv;      p.frel[5] = rel_msg;
    p.fpk[5] = PKA; p.fnoff[5] = 1024; p.fbf[5] = bfA + 1024;
    p.tW[0] = Wq + WD; p.tpk[0] = PKP;   // n-offset 0
    p.tW[1] = Wq;      p.tpk[1] = PKA;
    p.tW[2] = Wa;      p.tpk[2] = PK0;
    p.tW[3] = Wa + WD; p.tpk[3] = PK1;
    p.cin[0] = bq + D_; p.cout[0] = bfP;
    p.cin[1] = bq;      p.cout[1] = bfA;
    p.degree = degree; p.NT = NT;
    p.b1 = NA / 8;
    p.b2 = p.b1 + NP / 8;
    p.b3 = p.b2 + 6 * 513;
    p.b4 = p.b3 + 4 * 512;
    p.b5 = p.b4 + 2;
    int total = p.b5 + (NT + 511) / 512;
    prep_kernel<<<total, 512, 0, stream>>>(p);
  }

  // ---- CSR build ----
  {
    int th = 3 * E;
    hist_kernel<<<(th + 255) / 256, 256, 0, stream>>>(w_dst, c_dst, b_dst,
                                                      degree, E, NP);
    int nb = (NT + 255) / 256;
    scan1_kernel<<<nb, 256, 0, stream>>>(degree, starts, aux, NT);
    scan2_kernel<<<1, 1024, 0, stream>>>(aux, nb);
    scan3_kernel<<<nb, 256, 0, stream>>>(starts, cursor, aux, NT);
    scatter_kernel<<<(th + 255) / 256, 256, 0, stream>>>(
        w_src, w_dst, c_src, c_dst, b_src, b_dst, cursor, csr, E, NP);
  }

  // ---- 1 dispatch: both projection GEMMs (128x128 tiles, B-in-regs) ----
  {
    ProjArgs pa;
    pa.A0 = hA16; pa.A1 = hP16;
    pa.PK0 = PKA; pa.PK1 = PKP;
    pa.bias0 = bfA; pa.bias1 = bfP;
    pa.outs[0] = Aq;  pa.outs[1] = Akw; pa.outs[2] = Avw;
    pa.outs[3] = Pq;  pa.outs[4] = Pkc; pa.outs[5] = Pvc;
    pa.outs[6] = Pkb; pa.outs[7] = Pvb;
    pa.M0 = NA; pa.M1 = NP;
    pa.split = tA * 12;
    int nwg = pa.split + tP * 20;
    gemm_proj<<<nwg, 256, 0, stream>>>(pa);
  }

  // ---- 1 dispatch: all edge attention ----
  {
    long th = (long)(NP + NAp) * 64;
    attn_all<<<(int)((th + 255) / 256), 256, 0, stream>>>(
        Pq, Akw, Avw, Pkc, Pvc, Aq, Pkb, Pvb,
        csr, starts, degree, rel_pri, t16, NP, NA, NAp);
  }

  // ---- 1 dispatch: both output GEMMs (skip-mix epilogue) ----
  {
    OutArgs oa;
    oa.A = t16;
    oa.PK0 = PK0; oa.PK1 = PK1;
    oa.bias0 = ba; oa.bias1 = ba + D_;
    oa.H0 = h_author; oa.H1 = h_paper;
    oa.skip = skip;
    oa.o0 = out_a; oa.o1 = out_p;
    oa.mtsplit = tA; oa.NAp = NAp; oa.M0 = NA; oa.M1 = NP;
    int nwg = (tA + tP) * 4;
    gemm_out<<<nwg, 256, 0, stream>>>(oa);
  }
}

// Round 16
// 876.394 us; speedup vs baseline: 1.0114x; 1.0114x over previous
//
#include <hip/hip_runtime.h>
#include <math.h>

#define D_ 512
#define H_ 8

typedef short bf16x8 __attribute__((ext_vector_type(8)));
typedef float f32x4 __attribute__((ext_vector_type(4)));

__device__ __forceinline__ unsigned short f2bf(float x) {
  unsigned int u = __float_as_uint(x);
  unsigned int r = (u + 0x7fff + ((u >> 16) & 1)) >> 16;
  return (unsigned short)r;
}
__device__ __forceinline__ float bf2f(unsigned short b) {
  return __uint_as_float(((unsigned int)b) << 16);
}

// Packed-B index: PK[nt][kt][kk][njj][lane=q*16+rl][e]; frag elem j of the
// MFMA B-operand for (n, k-slice) = Bt[n][kt*64+kk*32+q*8+j].
__device__ __forceinline__ long pk_idx(int n, int k) {
  int nt = n >> 7, njj = (n >> 4) & 7, rl = n & 15;
  int kt = k >> 6, kk = (k >> 5) & 1, q = (k >> 3) & 3, e = k & 7;
  return ((((long)(nt * 8 + kt) * 2 + kk) * 8 + njj) * 64 + (q * 16 + rl)) * 8 + e;
}

// ================= prep: cvt + fuse-weights(->PK) + transposes(->PK) ========
struct PrepArgs {
  const float *hA, *hP;
  unsigned short *hA16, *hP16;
  const float *fWin[6], *fbin[6], *frel[6];
  unsigned short *fpk[6];
  int fnoff[6];
  float *fbf[6];
  const float *tW[4];
  unsigned short *tpk[4];
  const float *cin[2];
  float *cout[2];
  int *degree;
  int NT;
  int b1, b2, b3, b4, b5;
};

__global__ __launch_bounds__(512) void prep_kernel(PrepArgs p) {
  const int b = blockIdx.x, t = threadIdx.x;
  if (b < p.b2) {                    // bf16 convert (8 elems/thread)
    const float* in; unsigned short* out; long i;
    if (b < p.b1) { in = p.hA; out = p.hA16; i = (long)b * 512 + t; }
    else          { in = p.hP; out = p.hP16; i = (long)(b - p.b1) * 512 + t; }
    float4 a = ((const float4*)in)[i * 2];
    float4 c = ((const float4*)in)[i * 2 + 1];
    bf16x8 o;
    o[0] = (short)f2bf(a.x); o[1] = (short)f2bf(a.y);
    o[2] = (short)f2bf(a.z); o[3] = (short)f2bf(a.w);
    o[4] = (short)f2bf(c.x); o[5] = (short)f2bf(c.y);
    o[6] = (short)f2bf(c.z); o[7] = (short)f2bf(c.w);
    ((bf16x8*)out)[i] = o;
  } else if (b < p.b3) {             // fused rel-weight -> packed B
    int idx = b - p.b2;
    int job = idx / 513, row = idx - job * 513;   // row = k (512 => bias)
    int h = t >> 6, e = t & 63;
    const float* src = (row < D_) ? (p.fWin[job] + (long)row * D_) : p.fbin[job];
    const float* rl = p.frel[job] + h * 64 * 64;
    float acc = 0.f;
#pragma unroll 16
    for (int d = 0; d < 64; ++d)
      acc = fmaf(src[h * 64 + d], rl[d * 64 + e], acc);
    if (row < D_) p.fpk[job][pk_idx(p.fnoff[job] + t, row)] = f2bf(acc);
    else p.fbf[job][t] = acc;
  } else if (b < p.b4) {             // transpose-convert 512x512 -> packed B
    int idx = b - p.b3;
    int job = idx >> 9, n = idx & 511;
    p.tpk[job][pk_idx(n, t)] = f2bf(p.tW[job][(long)t * D_ + n]);
  } else if (b < p.b5) {             // bias copies
    int job = b - p.b4;
    p.cout[job][t] = p.cin[job][t];
  } else {                           // degree zero-fill
    int i = (b - p.b5) * 512 + t;
    if (i < p.NT) p.degree[i] = 0;
  }
}

// ================= CSR build: hist -> scan -> scatter ========================
__global__ void hist_kernel(const int* __restrict__ w_dst,
                            const int* __restrict__ c_dst,
                            const int* __restrict__ b_dst,
                            int* __restrict__ degree, int E, int NP) {
  int i = blockIdx.x * blockDim.x + threadIdx.x;
  if (i >= 3 * E) return;
  int r = i / E, e = i - r * E;
  int d, base;
  if (r == 0)      { d = w_dst[e]; base = 0; }
  else if (r == 1) { d = c_dst[e]; base = NP; }
  else             { d = b_dst[e]; base = 2 * NP; }
  atomicAdd(degree + base + d, 1);
}

__global__ void scan1_kernel(const int* __restrict__ in, int* __restrict__ out,
                             int* __restrict__ aux, int n) {
  __shared__ int tmp[256];
  int t = threadIdx.x;
  int i = blockIdx.x * 256 + t;
  int v = (i < n) ? in[i] : 0;
  tmp[t] = v;
  __syncthreads();
#pragma unroll
  for (int d = 1; d < 256; d <<= 1) {
    int add = (t >= d) ? tmp[t - d] : 0;
    __syncthreads();
    tmp[t] += add;
    __syncthreads();
  }
  if (i < n) out[i] = tmp[t] - v;   // exclusive
  if (t == 255) aux[blockIdx.x] = tmp[255];
}

__global__ void scan2_kernel(int* __restrict__ aux, int nb) {
  __shared__ int tmp[1024];
  int t = threadIdx.x;
  int v = (t < nb) ? aux[t] : 0;
  tmp[t] = v;
  __syncthreads();
#pragma unroll
  for (int d = 1; d < 1024; d <<= 1) {
    int add = (t >= d) ? tmp[t - d] : 0;
    __syncthreads();
    tmp[t] += add;
    __syncthreads();
  }
  if (t < nb) aux[t] = tmp[t] - v;  // exclusive block offsets
}

__global__ void scan3_kernel(int* __restrict__ starts, int* __restrict__ cursor,
                             const int* __restrict__ aux, int n) {
  int i = blockIdx.x * 256 + threadIdx.x;
  if (i >= n) return;
  int s = starts[i] + aux[blockIdx.x];
  starts[i] = s;
  cursor[i] = s;
}

__global__ void scatter_kernel(const int* __restrict__ w_src, const int* __restrict__ w_dst,
                               const int* __restrict__ c_src, const int* __restrict__ c_dst,
                               const int* __restrict__ b_src, const int* __restrict__ b_dst,
                               int* __restrict__ cursor, int* __restrict__ csr,
                               int E, int NP) {
  int i = blockIdx.x * blockDim.x + threadIdx.x;
  if (i >= 3 * E) return;
  int r = i / E, e = i - r * E;
  int s, d, base;
  if (r == 0)      { s = w_src[e]; d = w_dst[e]; base = 0; }
  else if (r == 1) { s = c_src[e]; d = c_dst[e]; base = NP; }
  else             { s = b_src[e]; d = b_dst[e]; base = 2 * NP; }
  int pos = atomicAdd(cursor + base + d, 1);
  csr[pos] = s;
}

// ================= fused per-node edge attention (papers + authors) ==========
__global__ __launch_bounds__(256) void attn_all(
    const unsigned short* __restrict__ Pq,
    const unsigned short* __restrict__ Akw, const unsigned short* __restrict__ Avw,
    const unsigned short* __restrict__ Pkc, const unsigned short* __restrict__ Pvc,
    const unsigned short* __restrict__ Aq,
    const unsigned short* __restrict__ Pkb, const unsigned short* __restrict__ Pvb,
    const int* __restrict__ csr, const int* __restrict__ starts,
    const int* __restrict__ degree, const float* __restrict__ pri,
    unsigned short* __restrict__ t16, int NP, int NA, int NAp) {
  long gid = (long)blockIdx.x * blockDim.x + threadIdx.x;
  int gw = (int)(gid >> 6);
  if (gw >= NP + NAp) return;
  int lane = threadIdx.x & 63;
  int h = lane >> 3, off = (lane & 7) << 3;

  const unsigned short* q;
  long orow;
  int node;
  const int paper = gw < NP;
  if (paper) {
    node = gw; q = Pq;
    orow = (long)(NAp + node) * D_ + h * 64 + off;
  } else {
    int aw = gw - NP;
    orow = (long)aw * D_ + h * 64 + off;
    if (aw >= NA) {                 // zero the alignment-pad rows
      bf16x8 z;
#pragma unroll
      for (int r = 0; r < 8; ++r) z[r] = 0;
      *(bf16x8*)(t16 + orow) = z;
      return;
    }
    node = aw; q = Aq;
  }

  bf16x8 qv = *(const bf16x8*)(q + (long)node * D_ + h * 64 + off);
  float qf[8];
#pragma unroll
  for (int r = 0; r < 8; ++r) qf[r] = bf2f((unsigned short)qv[r]);

  float res[8] = {};

  auto process = [&](const unsigned short* K, const unsigned short* V,
                     int nodeabs, float ps) {
    int st = starts[nodeabs], dg = degree[nodeabs];
    if (dg == 1) {
      // softmax over a single edge == 1: output is just the V row.
      int s = csr[st];
      bf16x8 vv = *(const bf16x8*)(V + (long)s * D_ + h * 64 + off);
#pragma unroll
      for (int r = 0; r < 8; ++r) res[r] += bf2f((unsigned short)vv[r]);
      return;
    }
    float m = -INFINITY, l = 0.f;
    float acc[8] = {};
    for (int i = 0; i < dg; ++i) {
      int s = csr[st + i];
      const long ro = (long)s * D_ + h * 64 + off;
      bf16x8 kv = *(const bf16x8*)(K + ro);
      bf16x8 vv = *(const bf16x8*)(V + ro);
      float dot = 0.f;
#pragma unroll
      for (int r = 0; r < 8; ++r)
        dot = fmaf(qf[r], bf2f((unsigned short)kv[r]), dot);
      dot += __shfl_xor(dot, 1);
      dot += __shfl_xor(dot, 2);
      dot += __shfl_xor(dot, 4);
      float sc = dot * ps;
      float mn = fmaxf(m, sc);
      float scale = __expf(m - mn);   // m=-inf first edge -> 0
      float pv = __expf(sc - mn);
      l = l * scale + pv;
#pragma unroll
      for (int r = 0; r < 8; ++r)
        acc[r] = acc[r] * scale + pv * bf2f((unsigned short)vv[r]);
      m = mn;
    }
    if (l > 0.f) {
      float inv = 1.f / l;
#pragma unroll
      for (int r = 0; r < 8; ++r) res[r] += acc[r] * inv;
    }
  };

  float outscale;
  if (paper) {
    process(Akw, Avw, node, pri[h] * 0.125f);
    process(Pkc, Pvc, NP + node, pri[8 + h] * 0.125f);
    outscale = 0.5f;
  } else {
    process(Pkb, Pvb, 2 * NP + node, pri[16 + h] * 0.125f);
    outscale = 1.0f;
  }

  bf16x8 o;
#pragma unroll
  for (int r = 0; r < 8; ++r) o[r] = (short)f2bf(res[r] * outscale);
  *(bf16x8*)(t16 + orow) = o;
}

// ================= MFMA GEMM: 128x128, A in 3-slot LDS ring, B reg-dbuf ======
// Fix vs round-15: B fragments for tile t+1 are issued right after tile t's
// top barrier (double-buffered bA/bB, statically named) so the ~200cyc L2
// latency hides under tile t's MFMA instead of sitting in the critical path.
// FIFO-exact vmcnt at tile top: t=0 -> 4; t=1..6 -> 12 (B(t)*8 + A(t+1)*4
// remain after A(t) drains); t=7 -> 8. A-path identical to round 15.
__device__ __forceinline__ void gload_lds16(const void* g, void* l) {
  __builtin_amdgcn_global_load_lds(
      (const __attribute__((address_space(1))) void*)g,
      (__attribute__((address_space(3))) void*)l, 16, 0, 0);
}

#define LOAD_B_(dst, tile)                                                    \
  _Pragma("unroll")                                                           \
  for (int kk = 0; kk < 2; ++kk)                                              \
    _Pragma("unroll")                                                         \
    for (int nj = 0; nj < 4; ++nj)                                            \
      dst[kk * 4 + nj] = *(const bf16x8*)(PKp +                               \
          ((long)((nt * 8 + (tile)) * 16 + kk * 8 + (wn >> 4) + nj) * 64 +    \
           lane) * 8);

#define MFMA_T(bc, ab)                                                        \
  __builtin_amdgcn_s_setprio(1);                                              \
  _Pragma("unroll")                                                           \
  for (int kk = 0; kk < 2; ++kk) {                                            \
    const int cs = (kk * 64 + qk * 16) ^ rx;                                  \
    bf16x8 af[4];                                                             \
    _Pragma("unroll")                                                         \
    for (int mi = 0; mi < 4; ++mi)                                            \
      af[mi] = *(const bf16x8*)((ab) + (wm + mi * 16 + rr) * 128 + cs);       \
    _Pragma("unroll")                                                         \
    for (int mi = 0; mi < 4; ++mi)                                            \
      _Pragma("unroll")                                                       \
      for (int nj = 0; nj < 4; ++nj)                                          \
        acc[mi][nj] = __builtin_amdgcn_mfma_f32_16x16x32_bf16(                \
            af[mi], (bc)[kk * 4 + nj], acc[mi][nj], 0, 0, 0);                 \
  }                                                                           \
  __builtin_amdgcn_s_setprio(0);

#define GEMM_CORE(A_PTR, PK_PTR)                                              \
  f32x4 acc[4][4] = {};                                                       \
  const unsigned short* PKp = (PK_PTR);                                       \
  const int rr = lane & 15;                                                   \
  const int qk = lane >> 4;                                                   \
  const int rx = (rr & 7) << 4;                                               \
  bf16x8 bA[8], bB[8];                                                        \
  auto STAGE_A = [&](int slot, int tile) {                                    \
    const int k0 = tile * 64 + swz;                                           \
    _Pragma("unroll")                                                         \
    for (int j = 0; j < 4; ++j) {                                             \
      int gr = bm + srow + j * 32;                                            \
      if (gr >= M) gr = M - 1;                                                \
      gload_lds16((A_PTR) + (long)gr * D_ + k0,                               \
                  &As[slot][j * 2048 + wave * 512]);                          \
    }                                                                         \
  };                                                                          \
  LOAD_B_(bA, 0)                                                              \
  STAGE_A(0, 0); STAGE_A(1, 1);                                               \
  _Pragma("unroll")                                                           \
  for (int t = 0; t < 8; ++t) {                                               \
    if (t == 0)     asm volatile("s_waitcnt vmcnt(4)" ::: "memory");          \
    else if (t < 7) asm volatile("s_waitcnt vmcnt(12)" ::: "memory");         \
    else            asm volatile("s_waitcnt vmcnt(8)" ::: "memory");          \
    __builtin_amdgcn_s_barrier();                                             \
    asm volatile("" ::: "memory");                                            \
    if ((t & 1) == 0) { if (t + 1 < 8) { LOAD_B_(bB, t + 1) } }               \
    else              { if (t + 1 < 8) { LOAD_B_(bA, t + 1) } }               \
    asm volatile("" ::: "memory");                                            \
    const char* ab = (const char*)&As[t % 3][0];                              \
    if (t + 2 < 8) STAGE_A((t + 2) % 3, t + 2);                               \
    if ((t & 1) == 0) { MFMA_T(bA, ab) } else { MFMA_T(bB, ab) }              \
    asm volatile("" ::: "memory");                                            \
  }

struct ProjArgs {
  const unsigned short *A0, *A1;
  const unsigned short *PK0, *PK1;
  const float *bias0, *bias1;
  void* outs[8];                    // 0-2 author, 3-7 paper
  int M0, M1, split;                // split = tA128*12
};

struct OutArgs {
  const unsigned short* A;          // combined t16
  const unsigned short *PK0, *PK1;
  const float *bias0, *bias1;
  const float *H0, *H1;
  const float* skip;
  float *o0, *o1;
  int mtsplit, NAp, M0, M1;
};

__global__ __launch_bounds__(256, 3) void gemm_proj(ProjArgs pa) {
  __shared__ unsigned short As[3][128 * 64];   // 48 KiB

  const int nwg = gridDim.x, orig = blockIdx.x;
  const int q8 = nwg >> 3, r8 = nwg & 7;
  const int xcd = orig & 7, pos = orig >> 3;
  const int wgid =
      (xcd < r8 ? xcd * (q8 + 1) : r8 * (q8 + 1) + (xcd - r8) * q8) + pos;

  int reg, mt, nt;
  if (wgid < pa.split) { reg = 0; mt = wgid / 12; nt = wgid - mt * 12; }
  else { int r = wgid - pa.split; reg = 1; mt = r / 20; nt = r - mt * 20; }
  const unsigned short* A  = reg ? pa.A1 : pa.A0;
  const unsigned short* PK = reg ? pa.PK1 : pa.PK0;
  const float* bias = reg ? pa.bias1 : pa.bias0;
  const int M = reg ? pa.M1 : pa.M0;
  const int bm = mt * 128, bn = nt * 128;

  const int tid = threadIdx.x;
  const int wave = tid >> 6, lane = tid & 63;
  const int wm = (wave >> 1) * 64;
  const int wn = (wave & 1) * 64;
  const int srow = tid >> 3;                    // 0..31
  const int swz = ((tid & 7) ^ (srow & 7)) * 8;

  GEMM_CORE(A, PK)

  const int cr = (lane >> 4) * 4;
  const int cc = lane & 15;
  const int matu = (bn + wn) >> 9;
  const int wcb = (bn + wn) & 511;
  unsigned short* ob16 = (unsigned short*)pa.outs[(reg ? 3 : 0) + matu];
#pragma unroll
  for (int mi = 0; mi < 4; ++mi) {
    int rowb = bm + wm + mi * 16 + cr;
#pragma unroll
    for (int nj = 0; nj < 4; ++nj) {
      float bb = bias[bn + wn + nj * 16 + cc];
#pragma unroll
      for (int r = 0; r < 4; ++r) {
        int row = rowb + r;
        if (row >= M) continue;
        ob16[(long)row * D_ + wcb + nj * 16 + cc] = f2bf(acc[mi][nj][r] + bb);
      }
    }
  }
}

__global__ __launch_bounds__(256, 3) void gemm_out(OutArgs oa) {
  __shared__ unsigned short As[3][128 * 64];

  const int nwg = gridDim.x, orig = blockIdx.x;
  const int q8 = nwg >> 3, r8 = nwg & 7;
  const int xcd = orig & 7, pos = orig >> 3;
  const int wgid =
      (xcd < r8 ? xcd * (q8 + 1) : r8 * (q8 + 1) + (xcd - r8) * q8) + pos;

  const int bmt = wgid >> 2;
  const int nt = wgid & 3;
  const int bn = nt * 128;
  const int reg = bmt >= oa.mtsplit;
  const int bm = (reg ? bmt - oa.mtsplit : bmt) * 128;   // region-local
  const int abase = reg ? oa.NAp : 0;
  const int M = reg ? oa.M1 : oa.M0;
  const unsigned short* A  = oa.A + (long)abase * D_;
  const unsigned short* PK = reg ? oa.PK1 : oa.PK0;
  const float* bias = reg ? oa.bias1 : oa.bias0;
  const float* Hres = reg ? oa.H1 : oa.H0;
  float* outp = reg ? oa.o1 : oa.o0;

  const int tid = threadIdx.x;
  const int wave = tid >> 6, lane = tid & 63;
  const int wm = (wave >> 1) * 64;
  const int wn = (wave & 1) * 64;
  const int srow = tid >> 3;
  const int swz = ((tid & 7) ^ (srow & 7)) * 8;

  GEMM_CORE(A, PK)

  float sv = oa.skip[reg];
  float alpha = 1.f / (1.f + expf(-sv));
  float beta = 1.f - alpha;
  const int cr = (lane >> 4) * 4;
  const int cc = lane & 15;
#pragma unroll
  for (int mi = 0; mi < 4; ++mi) {
    int rowb = bm + wm + mi * 16 + cr;
#pragma unroll
    for (int nj = 0; nj < 4; ++nj) {
      int col = bn + wn + nj * 16 + cc;
      float bb = bias[col];
#pragma unroll
      for (int r = 0; r < 4; ++r) {
        int row = rowb + r;
        if (row >= M) continue;
        float val = acc[mi][nj][r] + bb;
        val = val * alpha + Hres[(long)row * D_ + col] * beta;
        outp[(long)row * D_ + col] = val;
      }
    }
  }
}

// ================= launch =====================================================
extern "C" void kernel_launch(void* const* d_in, const int* in_sizes, int n_in,
                              void* d_out, int out_size, void* d_ws, size_t ws_size,
                              hipStream_t stream) {
  const float* h_author = (const float*)d_in[0];
  const float* h_paper  = (const float*)d_in[1];
  const int* w_src = (const int*)d_in[2];
  const int* w_dst = (const int*)d_in[3];
  const int* c_src = (const int*)d_in[4];
  const int* c_dst = (const int*)d_in[5];
  const int* b_src = (const int*)d_in[6];
  const int* b_dst = (const int*)d_in[7];
  const float* Wk = (const float*)d_in[8];
  const float* bk = (const float*)d_in[9];
  const float* Wq = (const float*)d_in[10];
  const float* bq = (const float*)d_in[11];
  const float* Wv = (const float*)d_in[12];
  const float* bv = (const float*)d_in[13];
  const float* Wa = (const float*)d_in[14];
  const float* ba = (const float*)d_in[15];
  const float* rel_att = (const float*)d_in[16];
  const float* rel_msg = (const float*)d_in[17];
  const float* rel_pri = (const float*)d_in[18];
  const float* skip = (const float*)d_in[19];

  const int NA = in_sizes[0] / D_;
  const int NP = in_sizes[1] / D_;
  const int E  = in_sizes[2];
  const int NT = 2 * NP + NA;
  const int tA = (NA + 127) / 128;       // author M tiles (BM=128)
  const int tP = (NP + 127) / 128;       // paper M tiles
  const int NAp = tA * 128;              // aligned author row count

  char* w = (char*)d_ws;
  auto alloc = [&](long bytes) {
    char* p = w;
    w += (bytes + 255) & ~255L;
    return p;
  };
  unsigned short* hA16 = (unsigned short*)alloc((long)NA * D_ * 2);
  unsigned short* hP16 = (unsigned short*)alloc((long)NP * D_ * 2);
  unsigned short* Pq   = (unsigned short*)alloc((long)NP * D_ * 2);
  unsigned short* Pkc  = (unsigned short*)alloc((long)NP * D_ * 2);
  unsigned short* Pvc  = (unsigned short*)alloc((long)NP * D_ * 2);
  unsigned short* Pkb  = (unsigned short*)alloc((long)NP * D_ * 2);
  unsigned short* Pvb  = (unsigned short*)alloc((long)NP * D_ * 2);
  unsigned short* Aq   = (unsigned short*)alloc((long)NA * D_ * 2);
  unsigned short* Akw  = (unsigned short*)alloc((long)NA * D_ * 2);
  unsigned short* Avw  = (unsigned short*)alloc((long)NA * D_ * 2);
  unsigned short* t16  = (unsigned short*)alloc((long)(NAp + NP) * D_ * 2);
  unsigned short* PKP  = (unsigned short*)alloc((long)2560 * D_ * 2);
  unsigned short* PKA  = (unsigned short*)alloc((long)1536 * D_ * 2);
  float* bfP           = (float*)alloc(2560 * 4);
  float* bfA           = (float*)alloc(1536 * 4);
  unsigned short* PK0  = (unsigned short*)alloc((long)D_ * D_ * 2);
  unsigned short* PK1  = (unsigned short*)alloc((long)D_ * D_ * 2);
  int* degree          = (int*)alloc((long)NT * 4);
  int* starts          = (int*)alloc((long)NT * 4);
  int* cursor          = (int*)alloc((long)NT * 4);
  int* csr             = (int*)alloc((long)3 * E * 4);
  int* aux             = (int*)alloc(((long)NT / 256 + 2) * 4);

  const long WD = (long)D_ * D_;
  const long RS = (long)H_ * 64 * 64;

  float* out_a = (float*)d_out;
  float* out_p = out_a + (long)NA * D_;

  // ---- 1 dispatch: all precompute ----
  {
    PrepArgs p;
    p.hA = h_author; p.hP = h_paper; p.hA16 = hA16; p.hP16 = hP16;
    p.fWin[0] = Wk + WD; p.fbin[0] = bk + D_; p.frel[0] = rel_att + RS;
    p.fpk[0] = PKP; p.fnoff[0] = 512;  p.fbf[0] = bfP + 512;
    p.fWin[1] = Wv + WD; p.fbin[1] = bv + D_; p.frel[1] = rel_msg + RS;
    p.fpk[1] = PKP; p.fnoff[1] = 1024; p.fbf[1] = bfP + 1024;
    p.fWin[2] = Wk + WD; p.fbin[2] = bk + D_; p.frel[2] = rel_att + 2 * RS;
    p.fpk[2] = PKP; p.fnoff[2] = 1536; p.fbf[2] = bfP + 1536;
    p.fWin[3] = Wv + WD; p.fbin[3] = bv + D_; p.frel[3] = rel_msg + 2 * RS;
    p.fpk[3] = PKP; p.fnoff[3] = 2048; p.fbf[3] = bfP + 2048;
    p.fWin[4] = Wk;      p.fbin[4] = bk;      p.frel[4] = rel_att;
    p.fpk[4] = PKA; p.fnoff[4] = 512;  p.fbf[4] = bfA + 512;
    p.fWin[5] = Wv;      p.fbin[5] = bv;      p.frel[5] = rel_msg;
    p.fpk[5] = PKA; p.fnoff[5] = 1024; p.fbf[5] = bfA + 1024;
    p.tW[0] = Wq + WD; p.tpk[0] = PKP;   // n-offset 0
    p.tW[1] = Wq;      p.tpk[1] = PKA;
    p.tW[2] = Wa;      p.tpk[2] = PK0;
    p.tW[3] = Wa + WD; p.tpk[3] = PK1;
    p.cin[0] = bq + D_; p.cout[0] = bfP;
    p.cin[1] = bq;      p.cout[1] = bfA;
    p.degree = degree; p.NT = NT;
    p.b1 = NA / 8;
    p.b2 = p.b1 + NP / 8;
    p.b3 = p.b2 + 6 * 513;
    p.b4 = p.b3 + 4 * 512;
    p.b5 = p.b4 + 2;
    int total = p.b5 + (NT + 511) / 512;
    prep_kernel<<<total, 512, 0, stream>>>(p);
  }

  // ---- CSR build ----
  {
    int th = 3 * E;
    hist_kernel<<<(th + 255) / 256, 256, 0, stream>>>(w_dst, c_dst, b_dst,
                                                      degree, E, NP);
    int nb = (NT + 255) / 256;
    scan1_kernel<<<nb, 256, 0, stream>>>(degree, starts, aux, NT);
    scan2_kernel<<<1, 1024, 0, stream>>>(aux, nb);
    scan3_kernel<<<nb, 256, 0, stream>>>(starts, cursor, aux, NT);
    scatter_kernel<<<(th + 255) / 256, 256, 0, stream>>>(
        w_src, w_dst, c_src, c_dst, b_src, b_dst, cursor, csr, E, NP);
  }

  // ---- 1 dispatch: both projection GEMMs (128x128 tiles, B reg-dbuf) ----
  {
    ProjArgs pa;
    pa.A0 = hA16; pa.A1 = hP16;
    pa.PK0 = PKA; pa.PK1 = PKP;
    pa.bias0 = bfA; pa.bias1 = bfP;
    pa.outs[0] = Aq;  pa.outs[1] = Akw; pa.outs[2] = Avw;
    pa.outs[3] = Pq;  pa.outs[4] = Pkc; pa.outs[5] = Pvc;
    pa.outs[6] = Pkb; pa.outs[7] = Pvb;
    pa.M0 = NA; pa.M1 = NP;
    pa.split = tA * 12;
    int nwg = pa.split + tP * 20;
    gemm_proj<<<nwg, 256, 0, stream>>>(pa);
  }

  // ---- 1 dispatch: all edge attention (deg-1 fast path) ----
  {
    long th = (long)(NP + NAp) * 64;
    attn_all<<<(int)((th + 255) / 256), 256, 0, stream>>>(
        Pq, Akw, Avw, Pkc, Pvc, Aq, Pkb, Pvb,
        csr, starts, degree, rel_pri, t16, NP, NA, NAp);
  }

  // ---- 1 dispatch: both output GEMMs (skip-mix epilogue) ----
  {
    OutArgs oa;
    oa.A = t16;
    oa.PK0 = PK0; oa.PK1 = PK1;
    oa.bias0 = ba; oa.bias1 = ba + D_;
    oa.H0 = h_author; oa.H1 = h_paper;
    oa.skip = skip;
    oa.o0 = out_a; oa.o1 = out_p;
    oa.mtsplit = tA; oa.NAp = NAp; oa.M0 = NA; oa.M1 = NP;
    int nwg = (tA + tP) * 4;
    gemm_out<<<nwg, 256, 0, stream>>>(oa);
  }
}